// Round 1
// baseline (160.257 us; speedup 1.0000x reference)
//
#include <hip/hip_runtime.h>

// VectorQuantizer on gfx950: fused bf16-MFMA distance GEMM + argmin + fp32 gather/loss.
// dist2[n,k] = ||x_n||^2 - 2 x_n.e_k + ||e_k||^2 ; argmin_k invariant to ||x_n||^2.
// Scores via mfma_f32_16x16x32_bf16 (A = x rows, B = codebook rows == B^T GEMM).
// Output 0: codebook[argmin] gathered in fp32 (exact). Output 1: 1.25*mean((q-x)^2) fp32.

typedef __attribute__((ext_vector_type(8))) short short8;
typedef __attribute__((ext_vector_type(4))) float f32x4;

#define VQ_D 64
#define MTILE 128

__device__ inline short f2bf(float f) {
  union { float f; unsigned u; } v; v.f = f;
  unsigned r = v.u + 0x7FFFu + ((v.u >> 16) & 1u);  // round-to-nearest-even
  return (short)(r >> 16);
}

// Prep: c2[k] = ||e_k||^2 (fp32), codebook -> bf16, zero the SSE accumulator.
__global__ void vq_prep(const float* __restrict__ cb, float* __restrict__ c2,
                        unsigned short* __restrict__ cbb, float* __restrict__ sse,
                        int K) {
  int k = blockIdx.x * blockDim.x + threadIdx.x;
  if (k == 0) *sse = 0.f;
  if (k >= K) return;
  const f32x4* row = (const f32x4*)(cb + (size_t)k * VQ_D);
  float s = 0.f;
#pragma unroll
  for (int i = 0; i < 16; ++i) {
    f32x4 v = row[i];
    s += v[0] * v[0] + v[1] * v[1] + v[2] * v[2] + v[3] * v[3];
    unsigned short* o = cbb + (size_t)k * VQ_D + i * 4;
    o[0] = (unsigned short)f2bf(v[0]);
    o[1] = (unsigned short)f2bf(v[1]);
    o[2] = (unsigned short)f2bf(v[2]);
    o[3] = (unsigned short)f2bf(v[3]);
  }
  c2[k] = s;
}

__global__ __launch_bounds__(256) void vq_main(
    const float* __restrict__ x, const float* __restrict__ cb,
    const float* __restrict__ c2, const unsigned short* __restrict__ cbb,
    float* __restrict__ out, float* __restrict__ sse_out, int K) {
  __shared__ int idxs[MTILE];
  __shared__ float redbuf[4];

  const int tid = threadIdx.x;
  const int wave = tid >> 6;
  const int lane = tid & 63;
  const int quad = lane >> 4;
  const int col = lane & 15;
  const long blockRow0 = (long)blockIdx.x * MTILE;
  const int waveRow0 = wave * 32;

  // ---- A fragments (bf16) : rows blockRow0+waveRow0 + mi*16 + (lane&15), k = ks*32+quad*8+j
  short8 Af[2][2];
#pragma unroll
  for (int mi = 0; mi < 2; ++mi) {
#pragma unroll
    for (int ks = 0; ks < 2; ++ks) {
      long row = blockRow0 + waveRow0 + mi * 16 + col;
      const f32x4* xp = (const f32x4*)(x + row * VQ_D + ks * 32 + quad * 8);
      f32x4 lo = xp[0];
      f32x4 hi = xp[1];
      short8 a;
      a[0] = f2bf(lo[0]); a[1] = f2bf(lo[1]); a[2] = f2bf(lo[2]); a[3] = f2bf(lo[3]);
      a[4] = f2bf(hi[0]); a[5] = f2bf(hi[1]); a[6] = f2bf(hi[2]); a[7] = f2bf(hi[3]);
      Af[mi][ks] = a;
    }
  }

  // ---- running argmin state: rows mi*16 + quad*4 + r  (C/D layout: row=quad*4+reg, col=lane&15)
  float bd[2][4];
  int bi[2][4];
#pragma unroll
  for (int mi = 0; mi < 2; ++mi)
#pragma unroll
    for (int r = 0; r < 4; ++r) { bd[mi][r] = 3.4e38f; bi[mi][r] = 0; }

  const int ntiles = K >> 4;  // 16 codes per tile
  for (int t = 0; t < ntiles; ++t) {
    const int code = (t << 4) + col;
    const short8 b0 = *(const short8*)(cbb + (size_t)code * VQ_D + quad * 8);
    const short8 b1 = *(const short8*)(cbb + (size_t)code * VQ_D + 32 + quad * 8);
    const float cc = c2[code];

    f32x4 acc0 = {0.f, 0.f, 0.f, 0.f};
    f32x4 acc1 = {0.f, 0.f, 0.f, 0.f};
    acc0 = __builtin_amdgcn_mfma_f32_16x16x32_bf16(Af[0][0], b0, acc0, 0, 0, 0);
    acc0 = __builtin_amdgcn_mfma_f32_16x16x32_bf16(Af[0][1], b1, acc0, 0, 0, 0);
    acc1 = __builtin_amdgcn_mfma_f32_16x16x32_bf16(Af[1][0], b0, acc1, 0, 0, 0);
    acc1 = __builtin_amdgcn_mfma_f32_16x16x32_bf16(Af[1][1], b1, acc1, 0, 0, 0);

#pragma unroll
    for (int r = 0; r < 4; ++r) {
      float d0 = fmaf(-2.f, acc0[r], cc);
      if (d0 < bd[0][r]) { bd[0][r] = d0; bi[0][r] = code; }
      float d1 = fmaf(-2.f, acc1[r], cc);
      if (d1 < bd[1][r]) { bd[1][r] = d1; bi[1][r] = code; }
    }
  }

  // ---- cross-lane argmin over the 16 columns within each quad group
#pragma unroll
  for (int off = 1; off < 16; off <<= 1) {
#pragma unroll
    for (int mi = 0; mi < 2; ++mi)
#pragma unroll
      for (int r = 0; r < 4; ++r) {
        float od = __shfl_xor(bd[mi][r], off);
        int oi = __shfl_xor(bi[mi][r], off);
        if (od < bd[mi][r] || (od == bd[mi][r] && oi < bi[mi][r])) {
          bd[mi][r] = od;
          bi[mi][r] = oi;
        }
      }
  }
  if (col == 0) {
#pragma unroll
    for (int mi = 0; mi < 2; ++mi)
#pragma unroll
      for (int r = 0; r < 4; ++r)
        idxs[waveRow0 + mi * 16 + quad * 4 + r] = bi[mi][r];
  }
  __syncthreads();

  // ---- gather quantized rows (exact fp32) + SSE for the loss. Coalesced float4.
  float sse = 0.f;
  const f32x4* cb4 = (const f32x4*)cb;
  const f32x4* x4 = (const f32x4*)x;
  f32x4* out4 = (f32x4*)out;
#pragma unroll
  for (int i = 0; i < 8; ++i) {
    int f = i * 256 + tid;      // float4 index within block tile (128 rows * 16)
    int row_l = f >> 4;
    int d4 = f & 15;
    int idx = idxs[row_l];
    f32x4 cv = cb4[(size_t)idx * 16 + d4];
    long gi = (blockRow0 + row_l) * 16 + d4;
    f32x4 xv = x4[gi];
    out4[gi] = cv;
    f32x4 dv = cv - xv;
    sse += dv[0] * dv[0] + dv[1] * dv[1] + dv[2] * dv[2] + dv[3] * dv[3];
  }
#pragma unroll
  for (int off = 32; off > 0; off >>= 1) sse += __shfl_down(sse, off);
  if (lane == 0) redbuf[wave] = sse;
  __syncthreads();
  if (tid == 0) {
    atomicAdd(sse_out, redbuf[0] + redbuf[1] + redbuf[2] + redbuf[3]);
  }
}

__global__ void vq_fin(const float* __restrict__ sse, float* __restrict__ loss_out,
                       long nelem) {
  loss_out[0] = 1.25f * (*sse) / (float)nelem;
}

extern "C" void kernel_launch(void* const* d_in, const int* in_sizes, int n_in,
                              void* d_out, int out_size, void* d_ws, size_t ws_size,
                              hipStream_t stream) {
  const float* x = (const float*)d_in[0];
  const float* cb = (const float*)d_in[1];
  float* out = (float*)d_out;

  const long n_elem = (long)in_sizes[0];     // 8388608
  const int nrows = (int)(n_elem / VQ_D);    // 131072
  const int K = in_sizes[1] / VQ_D;          // 1024

  char* ws = (char*)d_ws;
  float* sse = (float*)ws;                         // 4 B
  float* c2 = (float*)(ws + 256);                  // 4 KB
  unsigned short* cbb = (unsigned short*)(ws + 8192);  // 128 KB bf16 codebook

  vq_prep<<<dim3((K + 255) / 256), dim3(256), 0, stream>>>(cb, c2, cbb, sse, K);
  vq_main<<<dim3(nrows / MTILE), dim3(256), 0, stream>>>(x, cb, c2, cbb, out, sse, K);
  vq_fin<<<dim3(1), dim3(1), 0, stream>>>(sse, out + n_elem, n_elem);
}